// Round 4
// baseline (324.357 us; speedup 1.0000x reference)
//
#include <hip/hip_runtime.h>
#include <hip/hip_bf16.h>

// ---------- types ----------
typedef __bf16 bf16x8 __attribute__((ext_vector_type(8)));
typedef float  f32x4  __attribute__((ext_vector_type(4)));
typedef unsigned short ushort_t;
typedef unsigned int   uint_t;

// RNE float -> bf16 bits
__device__ __forceinline__ ushort_t f2bf(float f) {
    union { float f; uint_t u; } v; v.f = f;
    uint_t r = v.u + 0x7fffu + ((v.u >> 16) & 1u);
    return (ushort_t)(r >> 16);
}

// async global->LDS 16B per lane; lds ptr must be wave-uniform
__device__ __forceinline__ void async_copy16(const void* g, void* l) {
    __builtin_amdgcn_global_load_lds(
        (const __attribute__((address_space(1))) unsigned int*)g,
        (__attribute__((address_space(3))) unsigned int*)l, 16, 0, 0);
}

#define BATCH 4
#define NPTS  16384   // N (queries)
#define MPTS  4096    // M (ref points)
#define C1    128
#define C2    256
#define NCHUNK 8
#define CHUNK  (MPTS / NCHUNK)   // 512

// ---------- kernel 0: weight transpose->bf16 + BN fold ----------
__global__ __launch_bounds__(256) void prep_kernel(
    const float* __restrict__ w0, const float* __restrict__ w1,
    const float* __restrict__ g0, const float* __restrict__ b0,
    const float* __restrict__ m0, const float* __restrict__ v0,
    const float* __restrict__ g1, const float* __restrict__ b1,
    const float* __restrict__ m1, const float* __restrict__ v1,
    ushort_t* __restrict__ wt0, ushort_t* __restrict__ wt1,
    float* __restrict__ sc0, float* __restrict__ sh0,
    float* __restrict__ sc1, float* __restrict__ sh1) {
    int i = blockIdx.x * 256 + threadIdx.x;
    if (i < 256 * 384) {           // wt0[n][k] = bf16(w0[k][n]), w0 is [384,256]
        int n = i / 384, k = i % 384;
        wt0[i] = f2bf(w0[k * 256 + n]);
    }
    if (i < 128 * 256) {           // wt1[n][k] = bf16(w1[k][n]), w1 is [256,128]
        int n = i / 256, k = i % 256;
        wt1[i] = f2bf(w1[k * 128 + n]);
    }
    if (i < 256) { float s = g0[i] * rsqrtf(v0[i] + 1e-3f); sc0[i] = s; sh0[i] = b0[i] - m0[i] * s; }
    if (i < 128) { float s = g1[i] * rsqrtf(v1[i] + 1e-3f); sc1[i] = s; sh1[i] = b1[i] - m1[i] * s; }
}

// ---------- kernel 1a: partial 3-NN over one M-chunk ----------
// 2 queries/thread; candidate coords are wave-uniform -> scalar loads, no LDS.
// grid (NPTS/512, NCHUNK, BATCH) = (32,8,4) = 1024 blocks x 256 thr.
__global__ __launch_bounds__(256) void knn_partial(
    const float* __restrict__ xyz1, const float* __restrict__ xyz2,
    float* __restrict__ pd, int* __restrict__ pi) {
    const int t  = threadIdx.x;
    const int qb = blockIdx.x;
    const int c  = blockIdx.y;
    const int b  = blockIdx.z;
    const int n0 = qb * 512 + t;          // query A
    const int n1 = n0 + 256;              // query B
    const long baseA = ((long)b * NPTS + n0) * 3;
    const long baseB = ((long)b * NPTS + n1) * 3;
    const float qxa = xyz1[baseA], qya = xyz1[baseA + 1], qza = xyz1[baseA + 2];
    const float qxb = xyz1[baseB], qyb = xyz1[baseB + 1], qzb = xyz1[baseB + 2];

    float d0a = 3.4e38f, d1a = 3.4e38f, d2a = 3.4e38f;
    int   i0a = 0, i1a = 0, i2a = 0;
    float d0b = 3.4e38f, d1b = 3.4e38f, d2b = 3.4e38f;
    int   i0b = 0, i1b = 0, i2b = 0;

    auto ins = [](float d, int m, float& D0, int& I0, float& D1, int& I1,
                  float& D2, int& I2) {
        const bool c0 = d < D0, c1 = d < D1, c2 = d < D2;
        const float nd2 = c1 ? D1 : (c2 ? d : D2);
        const int   ni2 = c1 ? I1 : (c2 ? m : I2);
        const float nd1 = c0 ? D0 : (c1 ? d : D1);
        const int   ni1 = c0 ? I0 : (c1 ? m : I1);
        D0 = c0 ? d : D0; I0 = c0 ? m : I0;
        D1 = nd1; I1 = ni1; D2 = nd2; I2 = ni2;
    };

    const int mb = c * CHUNK;
    const float* __restrict__ gp = xyz2 + ((long)b * MPTS + mb) * 3;  // uniform
    for (int g = 0; g < CHUNK; g += 4) {
        // 4 candidates = 12 floats, wave-uniform addresses -> s_load
        const float4 P0 = *(const float4*)(gp + 3 * g);
        const float4 P1 = *(const float4*)(gp + 3 * g + 4);
        const float4 P2 = *(const float4*)(gp + 3 * g + 8);
        const float px[4] = {P0.x, P0.w, P1.z, P2.y};
        const float py[4] = {P0.y, P1.x, P1.w, P2.z};
        const float pz[4] = {P0.z, P1.y, P2.x, P2.w};
#pragma unroll
        for (int j = 0; j < 4; j++) {
            const int m = mb + g + j;
            {   // query A
                const float dx = px[j] - qxa, dy = py[j] - qya, dz = pz[j] - qza;
                const float d = dx * dx + dy * dy + dz * dz;
                ins(d, m, d0a, i0a, d1a, i1a, d2a, i2a);
            }
            {   // query B
                const float dx = px[j] - qxb, dy = py[j] - qyb, dz = pz[j] - qzb;
                const float d = dx * dx + dy * dy + dz * dz;
                ins(d, m, d0b, i0b, d1b, i1b, d2b, i2b);
            }
        }
    }
    const long poA = ((long)c * (BATCH * NPTS) + (long)b * NPTS + n0) * 3;
    const long poB = ((long)c * (BATCH * NPTS) + (long)b * NPTS + n1) * 3;
    pd[poA] = d0a; pd[poA + 1] = d1a; pd[poA + 2] = d2a;
    pi[poA] = i0a; pi[poA + 1] = i1a; pi[poA + 2] = i2a;
    pd[poB] = d0b; pd[poB + 1] = d1b; pd[poB + 2] = d2b;
    pi[poB] = i0b; pi[poB + 1] = i1b; pi[poB + 2] = i2b;
}

// ---------- kernel 1b: merge partials -> final idx + weights ----------
__global__ __launch_bounds__(256) void knn_merge(
    const float* __restrict__ pd, const int* __restrict__ pi,
    int* __restrict__ idx, float* __restrict__ wgt) {
    const long n = blockIdx.x * 256 + threadIdx.x;   // 0..BATCH*NPTS
    float d0 = 3.4e38f, d1 = 3.4e38f, d2 = 3.4e38f;
    int   i0 = 0, i1 = 0, i2 = 0;
#pragma unroll
    for (int c = 0; c < NCHUNK; c++) {
        const long po = ((long)c * (BATCH * NPTS) + n) * 3;
#pragma unroll
        for (int k = 0; k < 3; k++) {
            const float d = pd[po + k];
            const int   m = pi[po + k];
            const bool c0 = d < d0, c1 = d < d1, c2 = d < d2;
            const float nd2 = c1 ? d1 : (c2 ? d : d2);
            const int   ni2 = c1 ? i1 : (c2 ? m : i2);
            const float nd1 = c0 ? d0 : (c1 ? d : d1);
            const int   ni1 = c0 ? i0 : (c1 ? m : i1);
            d0 = c0 ? d : d0;  i0 = c0 ? m : i0;
            d1 = nd1; i1 = ni1; d2 = nd2; i2 = ni2;
        }
    }
    d0 = fmaxf(d0, 1e-10f); d1 = fmaxf(d1, 1e-10f); d2 = fmaxf(d2, 1e-10f);
    const float w0 = 1.f / d0, w1 = 1.f / d1, w2 = 1.f / d2;
    const float rs = 1.f / (w0 + w1 + w2);
    const long o = n * 3;
    idx[o] = i0; idx[o + 1] = i1; idx[o + 2] = i2;
    wgt[o] = w0 * rs; wgt[o + 1] = w1 * rs; wgt[o + 2] = w2 * rs;
}

// ---------- kernel 2: interpolate + concat -> x0 bf16 [65536, 384] ----------
__global__ __launch_bounds__(256) void interp_kernel(
    const float* __restrict__ points1, const float* __restrict__ points2,
    const int* __restrict__ idx, const float* __restrict__ wgt,
    ushort_t* __restrict__ x0) {
    const int wave = (blockIdx.x * 256 + threadIdx.x) >> 6;  // one point per wave
    const int lane = threadIdx.x & 63;
    const int b = wave >> 14;            // 16384 points per batch
    const int n = wave & 16383;
    const long o = (long)wave * 3;
    int i0 = idx[o], i1 = idx[o + 1], i2 = idx[o + 2];
    // defensive clamp: a bad index becomes a wrong value, not a segfault
    i0 = min(max(i0, 0), MPTS - 1);
    i1 = min(max(i1, 0), MPTS - 1);
    i2 = min(max(i2, 0), MPTS - 1);
    const float w0 = wgt[o], w1 = wgt[o + 1], w2 = wgt[o + 2];
    const float4* p0 = (const float4*)(points2 + ((long)b * MPTS + i0) * C2);
    const float4* p1 = (const float4*)(points2 + ((long)b * MPTS + i1) * C2);
    const float4* p2 = (const float4*)(points2 + ((long)b * MPTS + i2) * C2);
    float4 a = p0[lane], bb = p1[lane], c = p2[lane];
    ushort4 u;
    u.x = f2bf(w0 * a.x + w1 * bb.x + w2 * c.x);
    u.y = f2bf(w0 * a.y + w1 * bb.y + w2 * c.y);
    u.z = f2bf(w0 * a.z + w1 * bb.z + w2 * c.z);
    u.w = f2bf(w0 * a.w + w1 * bb.w + w2 * c.w);
    ((ushort4*)(x0 + (long)wave * 384))[lane] = u;           // cols 4*lane..4*lane+3
    const float2* q = (const float2*)(points1 + ((long)b * NPTS + n) * C1);
    float2 t = q[lane];
    uint_t packed = (uint_t)f2bf(t.x) | ((uint_t)f2bf(t.y) << 16);
    ((uint_t*)(x0 + (long)wave * 384 + 256))[lane] = packed; // cols 256+2*lane, +1
}

// ---------- kernel 3/4: bf16 MFMA GEMM + BN + ReLU ----------
// C[row][col] = relu(scale[col]*(A[row][:] . Bt[col][:]) + shift[col])
template <int K, bool OUT_BF16>
__global__ __launch_bounds__(256) void gemm_bn_relu(
    const ushort_t* __restrict__ A,   // [Mrows, K] bf16 row-major
    const ushort_t* __restrict__ Bt,  // [NCOLS, K] bf16 row-major (B transposed)
    const float* __restrict__ scale, const float* __restrict__ shift,
    void* __restrict__ outp, int ldout) {
    __shared__ ushort_t lds[8192];    // A tile 128x32 (8KB) + B tile 128x32 (8KB)
    ushort_t* ldsA = lds;
    ushort_t* ldsB = lds + 4096;
    const int tid  = threadIdx.x;
    const int wv   = tid >> 6;
    const int lane = tid & 63;
    const int q    = lane >> 4, l16 = lane & 15;
    const int rowBase = blockIdx.x * 128;
    const int colBase = blockIdx.y * 128;
    const int wrow = (wv & 1) * 64, wcol = (wv >> 1) * 64;
    f32x4 acc[4][4] = {};

    for (int kk = 0; kk < K; kk += 32) {
#pragma unroll
        for (int ch = 0; ch < 2; ch++) {
            const int linear = ch * 4096 + tid * 16;   // byte offset within 8KB tile
            const int row = linear >> 6;               // 64B per row (32 bf16)
            const int brow = linear & 63;
            const char* ga = (const char*)A + ((long)(rowBase + row) * K + kk) * 2 + brow;
            async_copy16(ga, (char*)ldsA + ch * 4096 + wv * 1024);
            const char* gb = (const char*)Bt + ((long)(colBase + row) * K + kk) * 2 + brow;
            async_copy16(gb, (char*)ldsB + ch * 4096 + wv * 1024);
        }
        __syncthreads();
        bf16x8 af[4], bfr[4];
#pragma unroll
        for (int t = 0; t < 4; t++) {
            const int r = wrow + t * 16 + l16;
            af[t]  = *(const bf16x8*)((const char*)ldsA + r * 64 + q * 16);
            const int c = wcol + t * 16 + l16;
            bfr[t] = *(const bf16x8*)((const char*)ldsB + c * 64 + q * 16);
        }
#pragma unroll
        for (int tr = 0; tr < 4; tr++)
#pragma unroll
            for (int tc = 0; tc < 4; tc++)
                acc[tr][tc] = __builtin_amdgcn_mfma_f32_16x16x32_bf16(af[tr], bfr[tc], acc[tr][tc], 0, 0, 0);
        __syncthreads();
    }
    // epilogue: C/D layout col=lane&15, row=(lane>>4)*4+r
#pragma unroll
    for (int tc = 0; tc < 4; tc++) {
        const int col = colBase + wcol + tc * 16 + l16;
        const float sc = scale[col], sh = shift[col];
#pragma unroll
        for (int tr = 0; tr < 4; tr++) {
            const int row0 = rowBase + wrow + tr * 16 + q * 4;
#pragma unroll
            for (int r = 0; r < 4; r++) {
                float v = acc[tr][tc][r];
                v = fmaxf(v * sc + sh, 0.0f);
                const long off = (long)(row0 + r) * ldout + col;
                if (OUT_BF16) ((ushort_t*)outp)[off] = f2bf(v);
                else          ((float*)outp)[off]    = v;
            }
        }
    }
}

// ---------- launch ----------
extern "C" void kernel_launch(void* const* d_in, const int* in_sizes, int n_in,
                              void* d_out, int out_size, void* d_ws, size_t ws_size,
                              hipStream_t stream) {
    const float* xyz1    = (const float*)d_in[0];
    const float* xyz2    = (const float*)d_in[1];
    const float* points1 = (const float*)d_in[2];
    const float* points2 = (const float*)d_in[3];
    const float* w0 = (const float*)d_in[4];
    const float* g0 = (const float*)d_in[5];
    const float* b0 = (const float*)d_in[6];
    const float* m0 = (const float*)d_in[7];
    const float* v0 = (const float*)d_in[8];
    const float* w1 = (const float*)d_in[9];
    const float* g1 = (const float*)d_in[10];
    const float* b1 = (const float*)d_in[11];
    const float* m1 = (const float*)d_in[12];
    const float* v1 = (const float*)d_in[13];

    char* ws = (char*)d_ws;
    int*      idx = (int*)ws;                         // 786432 B
    float*    wgt = (float*)(ws + 786432);            // 786432 B
    ushort_t* wt0 = (ushort_t*)(ws + 1572864);        // 196608 B
    ushort_t* wt1 = (ushort_t*)(ws + 1769472);        // 65536 B
    float*    sc0 = (float*)(ws + 1835008);
    float*    sh0 = sc0 + 256;
    float*    sc1 = sh0 + 256;
    float*    sh1 = sc1 + 128;
    ushort_t* x0  = (ushort_t*)(ws + 2097152);        // 65536*384*2 = 50331648 B
    ushort_t* y1  = (ushort_t*)(ws + 2097152 + 50331648); // 65536*256*2 = 33554432 B
    // knn partials aliased into the x0 region (fully consumed by knn_merge
    // before interp_kernel writes x0). BYTE offsets; each needs
    // 8*65536*3*4 B = 6,291,456 B.
    float* pd = (float*)(ws + 2097152);
    int*   pi = (int*)(ws + 2097152 + 6291456);

    prep_kernel<<<384, 256, 0, stream>>>(w0, w1, g0, b0, m0, v0, g1, b1, m1, v1,
                                         wt0, wt1, sc0, sh0, sc1, sh1);
    knn_partial<<<dim3(NPTS / 512, NCHUNK, BATCH), 256, 0, stream>>>(xyz1, xyz2, pd, pi);
    knn_merge<<<(BATCH * NPTS) / 256, 256, 0, stream>>>(pd, pi, idx, wgt);
    interp_kernel<<<(BATCH * NPTS) / 4, 256, 0, stream>>>(points1, points2, idx, wgt, x0);
    gemm_bn_relu<384, true ><<<dim3((BATCH * NPTS) / 128, 2), 256, 0, stream>>>(
        x0, wt0, sc0, sh0, (void*)y1, 256);
    gemm_bn_relu<256, false><<<dim3((BATCH * NPTS) / 128, 1), 256, 0, stream>>>(
        y1, wt1, sc1, sh1, d_out, 128);
}

// Round 5
// 262.935 us; speedup vs baseline: 1.2336x; 1.2336x over previous
//
#include <hip/hip_runtime.h>
#include <hip/hip_bf16.h>

// ---------- types ----------
typedef __bf16 bf16x8 __attribute__((ext_vector_type(8)));
typedef float  f32x4  __attribute__((ext_vector_type(4)));
typedef unsigned short ushort_t;
typedef unsigned int   uint_t;

// RNE float -> bf16 bits
__device__ __forceinline__ ushort_t f2bf(float f) {
    union { float f; uint_t u; } v; v.f = f;
    uint_t r = v.u + 0x7fffu + ((v.u >> 16) & 1u);
    return (ushort_t)(r >> 16);
}

// async global->LDS 16B per lane; lds ptr must be wave-uniform
__device__ __forceinline__ void async_copy16(const void* g, void* l) {
    __builtin_amdgcn_global_load_lds(
        (const __attribute__((address_space(1))) unsigned int*)g,
        (__attribute__((address_space(3))) unsigned int*)l, 16, 0, 0);
}

#define BATCH 4
#define NPTS  16384   // N (queries)
#define MPTS  4096    // M (ref points)
#define C1    128
#define C2    256
#define NCHUNK 4
#define CHUNK  (MPTS / NCHUNK)   // 1024

// ---------- kernel 0: weight transpose->bf16 + BN fold ----------
__global__ __launch_bounds__(256) void prep_kernel(
    const float* __restrict__ w0, const float* __restrict__ w1,
    const float* __restrict__ g0, const float* __restrict__ b0,
    const float* __restrict__ m0, const float* __restrict__ v0,
    const float* __restrict__ g1, const float* __restrict__ b1,
    const float* __restrict__ m1, const float* __restrict__ v1,
    ushort_t* __restrict__ wt0, ushort_t* __restrict__ wt1,
    float* __restrict__ sc0, float* __restrict__ sh0,
    float* __restrict__ sc1, float* __restrict__ sh1) {
    int i = blockIdx.x * 256 + threadIdx.x;
    if (i < 256 * 384) {           // wt0[n][k] = bf16(w0[k][n]), w0 is [384,256]
        int n = i / 384, k = i % 384;
        wt0[i] = f2bf(w0[k * 256 + n]);
    }
    if (i < 128 * 256) {           // wt1[n][k] = bf16(w1[k][n]), w1 is [256,128]
        int n = i / 256, k = i % 256;
        wt1[i] = f2bf(w1[k * 128 + n]);
    }
    if (i < 256) { float s = g0[i] * rsqrtf(v0[i] + 1e-3f); sc0[i] = s; sh0[i] = b0[i] - m0[i] * s; }
    if (i < 128) { float s = g1[i] * rsqrtf(v1[i] + 1e-3f); sc1[i] = s; sh1[i] = b1[i] - m1[i] * s; }
}

// ---------- kernel 1a: partial 3-NN over one M-chunk ----------
// Round-5 version: expansion distance (3 FMA via |p|^2 staged in LDS and
// -2q premultiplied) + ballot-gated sorted insert (wave-uniform branch).
// Scores s = |p|^2 - 2 q.p  (order-equivalent to d^2 per query; |q|^2 added
// in knn_merge). grid (64, NCHUNK, BATCH) x 256 thr, 1 query/thread.
__global__ __launch_bounds__(256) void knn_partial(
    const float* __restrict__ xyz1, const float* __restrict__ xyz2,
    float* __restrict__ pd, int* __restrict__ pi) {
    __shared__ __align__(16) float sx[CHUNK], sy[CHUNK], sz[CHUNK], sw[CHUNK];
    const int t  = threadIdx.x;
    const int qb = blockIdx.x;
    const int c  = blockIdx.y;
    const int b  = blockIdx.z;
    // stage chunk (AoS global -> SoA LDS, plus |p|^2)
#pragma unroll
    for (int j = 0; j < CHUNK / 256; j++) {
        const int m = j * 256 + t;
        const float* g = xyz2 + ((long)b * MPTS + c * CHUNK + m) * 3;
        const float x = g[0], y = g[1], z = g[2];
        sx[m] = x; sy[m] = y; sz[m] = z; sw[m] = x * x + y * y + z * z;
    }
    __syncthreads();
    const int n = qb * 256 + t;
    const long base = ((long)b * NPTS + n) * 3;
    const float qx = xyz1[base], qy = xyz1[base + 1], qz = xyz1[base + 2];
    const float nx = -2.f * qx, ny = -2.f * qy, nz = -2.f * qz;
    float d0 = 3.4e38f, d1 = 3.4e38f, d2 = 3.4e38f;
    int   i0 = 0, i1 = 0, i2 = 0;
    const int mb = c * CHUNK;
    for (int g = 0; g < CHUNK; g += 4) {
        const float4 X = *(const float4*)&sx[g];
        const float4 Y = *(const float4*)&sy[g];
        const float4 Z = *(const float4*)&sz[g];
        const float4 W = *(const float4*)&sw[g];
        const float xs[4] = {X.x, X.y, X.z, X.w};
        const float ys[4] = {Y.x, Y.y, Y.z, Y.w};
        const float zs[4] = {Z.x, Z.y, Z.z, Z.w};
        const float ws[4] = {W.x, W.y, W.z, W.w};
#pragma unroll
        for (int j = 0; j < 4; j++) {
            const float s = fmaf(xs[j], nx, fmaf(ys[j], ny, fmaf(zs[j], nz, ws[j])));
            // wave-uniform gate: insert path only when some lane improves
            if (__ballot(s < d2)) {
                const int m = mb + g + j;
                const bool c0 = s < d0, c1 = s < d1, c2 = s < d2;
                const float nd2 = c1 ? d1 : (c2 ? s : d2);
                const int   ni2 = c1 ? i1 : (c2 ? m : i2);
                const float nd1 = c0 ? d0 : (c1 ? s : d1);
                const int   ni1 = c0 ? i0 : (c1 ? m : i1);
                d0 = c0 ? s : d0; i0 = c0 ? m : i0;
                d1 = nd1; i1 = ni1; d2 = nd2; i2 = ni2;
            }
        }
    }
    const long po = ((long)c * (BATCH * NPTS) + (long)b * NPTS + n) * 3;
    pd[po] = d0; pd[po + 1] = d1; pd[po + 2] = d2;
    pi[po] = i0; pi[po + 1] = i1; pi[po + 2] = i2;
}

// ---------- kernel 1b: merge partials -> final idx + weights ----------
__global__ __launch_bounds__(256) void knn_merge(
    const float* __restrict__ xyz1,
    const float* __restrict__ pd, const int* __restrict__ pi,
    int* __restrict__ idx, float* __restrict__ wgt) {
    const long n = blockIdx.x * 256 + threadIdx.x;   // 0..BATCH*NPTS
    float d0 = 3.4e38f, d1 = 3.4e38f, d2 = 3.4e38f;
    int   i0 = 0, i1 = 0, i2 = 0;
#pragma unroll
    for (int c = 0; c < NCHUNK; c++) {
        const long po = ((long)c * (BATCH * NPTS) + n) * 3;
#pragma unroll
        for (int k = 0; k < 3; k++) {
            const float d = pd[po + k];
            const int   m = pi[po + k];
            const bool c0 = d < d0, c1 = d < d1, c2 = d < d2;
            const float nd2 = c1 ? d1 : (c2 ? d : d2);
            const int   ni2 = c1 ? i1 : (c2 ? m : i2);
            const float nd1 = c0 ? d0 : (c1 ? d : d1);
            const int   ni1 = c0 ? i0 : (c1 ? m : i1);
            d0 = c0 ? d : d0;  i0 = c0 ? m : i0;
            d1 = nd1; i1 = ni1; d2 = nd2; i2 = ni2;
        }
    }
    // scores -> distances: d^2 = s + |q|^2 (clamped like reference)
    const float qx = xyz1[n * 3], qy = xyz1[n * 3 + 1], qz = xyz1[n * 3 + 2];
    const float qn = qx * qx + qy * qy + qz * qz;
    d0 = fmaxf(d0 + qn, 1e-10f);
    d1 = fmaxf(d1 + qn, 1e-10f);
    d2 = fmaxf(d2 + qn, 1e-10f);
    const float w0 = 1.f / d0, w1 = 1.f / d1, w2 = 1.f / d2;
    const float rs = 1.f / (w0 + w1 + w2);
    const long o = n * 3;
    idx[o] = i0; idx[o + 1] = i1; idx[o + 2] = i2;
    wgt[o] = w0 * rs; wgt[o + 1] = w1 * rs; wgt[o + 2] = w2 * rs;
}

// ---------- kernel 2: interpolate + concat -> x0 bf16 [65536, 384] ----------
__global__ __launch_bounds__(256) void interp_kernel(
    const float* __restrict__ points1, const float* __restrict__ points2,
    const int* __restrict__ idx, const float* __restrict__ wgt,
    ushort_t* __restrict__ x0) {
    const int wave = (blockIdx.x * 256 + threadIdx.x) >> 6;  // one point per wave
    const int lane = threadIdx.x & 63;
    const int b = wave >> 14;            // 16384 points per batch
    const int n = wave & 16383;
    const long o = (long)wave * 3;
    int i0 = idx[o], i1 = idx[o + 1], i2 = idx[o + 2];
    // defensive clamp: a bad index becomes a wrong value, not a segfault
    i0 = min(max(i0, 0), MPTS - 1);
    i1 = min(max(i1, 0), MPTS - 1);
    i2 = min(max(i2, 0), MPTS - 1);
    const float w0 = wgt[o], w1 = wgt[o + 1], w2 = wgt[o + 2];
    const float4* p0 = (const float4*)(points2 + ((long)b * MPTS + i0) * C2);
    const float4* p1 = (const float4*)(points2 + ((long)b * MPTS + i1) * C2);
    const float4* p2 = (const float4*)(points2 + ((long)b * MPTS + i2) * C2);
    float4 a = p0[lane], bb = p1[lane], c = p2[lane];
    ushort4 u;
    u.x = f2bf(w0 * a.x + w1 * bb.x + w2 * c.x);
    u.y = f2bf(w0 * a.y + w1 * bb.y + w2 * c.y);
    u.z = f2bf(w0 * a.z + w1 * bb.z + w2 * c.z);
    u.w = f2bf(w0 * a.w + w1 * bb.w + w2 * c.w);
    ((ushort4*)(x0 + (long)wave * 384))[lane] = u;           // cols 4*lane..4*lane+3
    const float2* q = (const float2*)(points1 + ((long)b * NPTS + n) * C1);
    float2 t = q[lane];
    uint_t packed = (uint_t)f2bf(t.x) | ((uint_t)f2bf(t.y) << 16);
    ((uint_t*)(x0 + (long)wave * 384 + 256))[lane] = packed; // cols 256+2*lane, +1
}

// ---------- kernel 3/4: bf16 MFMA GEMM + BN + ReLU ----------
// C[row][col] = relu(scale[col]*(A[row][:] . Bt[col][:]) + shift[col])
template <int K, bool OUT_BF16>
__global__ __launch_bounds__(256) void gemm_bn_relu(
    const ushort_t* __restrict__ A,   // [Mrows, K] bf16 row-major
    const ushort_t* __restrict__ Bt,  // [NCOLS, K] bf16 row-major (B transposed)
    const float* __restrict__ scale, const float* __restrict__ shift,
    void* __restrict__ outp, int ldout) {
    __shared__ ushort_t lds[8192];    // A tile 128x32 (8KB) + B tile 128x32 (8KB)
    ushort_t* ldsA = lds;
    ushort_t* ldsB = lds + 4096;
    const int tid  = threadIdx.x;
    const int wv   = tid >> 6;
    const int lane = tid & 63;
    const int q    = lane >> 4, l16 = lane & 15;
    const int rowBase = blockIdx.x * 128;
    const int colBase = blockIdx.y * 128;
    const int wrow = (wv & 1) * 64, wcol = (wv >> 1) * 64;
    f32x4 acc[4][4] = {};

    for (int kk = 0; kk < K; kk += 32) {
#pragma unroll
        for (int ch = 0; ch < 2; ch++) {
            const int linear = ch * 4096 + tid * 16;   // byte offset within 8KB tile
            const int row = linear >> 6;               // 64B per row (32 bf16)
            const int brow = linear & 63;
            const char* ga = (const char*)A + ((long)(rowBase + row) * K + kk) * 2 + brow;
            async_copy16(ga, (char*)ldsA + ch * 4096 + wv * 1024);
            const char* gb = (const char*)Bt + ((long)(colBase + row) * K + kk) * 2 + brow;
            async_copy16(gb, (char*)ldsB + ch * 4096 + wv * 1024);
        }
        __syncthreads();
        bf16x8 af[4], bfr[4];
#pragma unroll
        for (int t = 0; t < 4; t++) {
            const int r = wrow + t * 16 + l16;
            af[t]  = *(const bf16x8*)((const char*)ldsA + r * 64 + q * 16);
            const int c = wcol + t * 16 + l16;
            bfr[t] = *(const bf16x8*)((const char*)ldsB + c * 64 + q * 16);
        }
#pragma unroll
        for (int tr = 0; tr < 4; tr++)
#pragma unroll
            for (int tc = 0; tc < 4; tc++)
                acc[tr][tc] = __builtin_amdgcn_mfma_f32_16x16x32_bf16(af[tr], bfr[tc], acc[tr][tc], 0, 0, 0);
        __syncthreads();
    }
    // epilogue: C/D layout col=lane&15, row=(lane>>4)*4+r
#pragma unroll
    for (int tc = 0; tc < 4; tc++) {
        const int col = colBase + wcol + tc * 16 + l16;
        const float sc = scale[col], sh = shift[col];
#pragma unroll
        for (int tr = 0; tr < 4; tr++) {
            const int row0 = rowBase + wrow + tr * 16 + q * 4;
#pragma unroll
            for (int r = 0; r < 4; r++) {
                float v = acc[tr][tc][r];
                v = fmaxf(v * sc + sh, 0.0f);
                const long off = (long)(row0 + r) * ldout + col;
                if (OUT_BF16) ((ushort_t*)outp)[off] = f2bf(v);
                else          ((float*)outp)[off]    = v;
            }
        }
    }
}

// ---------- launch ----------
extern "C" void kernel_launch(void* const* d_in, const int* in_sizes, int n_in,
                              void* d_out, int out_size, void* d_ws, size_t ws_size,
                              hipStream_t stream) {
    const float* xyz1    = (const float*)d_in[0];
    const float* xyz2    = (const float*)d_in[1];
    const float* points1 = (const float*)d_in[2];
    const float* points2 = (const float*)d_in[3];
    const float* w0 = (const float*)d_in[4];
    const float* g0 = (const float*)d_in[5];
    const float* b0 = (const float*)d_in[6];
    const float* m0 = (const float*)d_in[7];
    const float* v0 = (const float*)d_in[8];
    const float* w1 = (const float*)d_in[9];
    const float* g1 = (const float*)d_in[10];
    const float* b1 = (const float*)d_in[11];
    const float* m1 = (const float*)d_in[12];
    const float* v1 = (const float*)d_in[13];

    char* ws = (char*)d_ws;
    int*      idx = (int*)ws;                         // 786432 B
    float*    wgt = (float*)(ws + 786432);            // 786432 B
    ushort_t* wt0 = (ushort_t*)(ws + 1572864);        // 196608 B
    ushort_t* wt1 = (ushort_t*)(ws + 1769472);        // 65536 B
    float*    sc0 = (float*)(ws + 1835008);
    float*    sh0 = sc0 + 256;
    float*    sc1 = sh0 + 256;
    float*    sh1 = sc1 + 128;
    ushort_t* x0  = (ushort_t*)(ws + 2097152);        // 65536*384*2 = 50331648 B
    ushort_t* y1  = (ushort_t*)(ws + 2097152 + 50331648); // 65536*256*2 = 33554432 B
    // knn partials aliased into the x0 region (fully consumed by knn_merge
    // before interp_kernel writes x0). BYTE offsets; NCHUNK*65536*3*4 B
    // = 3,145,728 B each (regions sized for up to 8 chunks).
    float* pd = (float*)(ws + 2097152);
    int*   pi = (int*)(ws + 2097152 + 6291456);

    prep_kernel<<<384, 256, 0, stream>>>(w0, w1, g0, b0, m0, v0, g1, b1, m1, v1,
                                         wt0, wt1, sc0, sh0, sc1, sh1);
    knn_partial<<<dim3(NPTS / 256, NCHUNK, BATCH), 256, 0, stream>>>(xyz1, xyz2, pd, pi);
    knn_merge<<<(BATCH * NPTS) / 256, 256, 0, stream>>>(xyz1, pd, pi, idx, wgt);
    interp_kernel<<<(BATCH * NPTS) / 4, 256, 0, stream>>>(points1, points2, idx, wgt, x0);
    gemm_bn_relu<384, true ><<<dim3((BATCH * NPTS) / 128, 2), 256, 0, stream>>>(
        x0, wt0, sc0, sh0, (void*)y1, 256);
    gemm_bn_relu<256, false><<<dim3((BATCH * NPTS) / 128, 1), 256, 0, stream>>>(
        y1, wt1, sc1, sh1, d_out, 128);
}